// Round 9
// baseline (256.417 us; speedup 1.0000x reference)
//
#include <hip/hip_runtime.h>
#include <hip/hip_bf16.h>
#include <math.h>

#define SEQ_LEN 128
#define BATCH   32
#define T       32
#define TT      (T*T)     // 1024
#define TTT     (T*T*T)   // 32768
#define START   30
#define END     31

#define LOG2E   1.44269504088896f
#define OFF4    5.77078016355587f   // 4 * log2(e)

#define SSTR 33   // Sld row stride (words)
#define TSTR 36   // tile row stride (words, 16B-aligned rows)

typedef unsigned long long u64;

__device__ __forceinline__ u64 pt_pack(int tag, float v) {
    union { float f; unsigned int u; } c; c.f = v;
    return ((u64)(unsigned int)tag << 32) | (u64)c.u;
}
__device__ __forceinline__ float pt_val(u64 w) {
    union { unsigned int u; float f; } c; c.u = (unsigned int)w; return c.f;
}
__device__ __forceinline__ int pt_tag(u64 w) { return (int)(w >> 32); }

__device__ __forceinline__ u64 ald64(const u64* p) {
    return __hip_atomic_load(p, __ATOMIC_RELAXED, __HIP_MEMORY_SCOPE_AGENT);
}
__device__ __forceinline__ void ast64(u64* p, u64 v) {
    __hip_atomic_store(p, v, __ATOMIC_RELAXED, __HIP_MEMORY_SCOPE_AGENT);
}

#define BLOCK_SYNC() do {                                   \
    asm volatile("s_waitcnt lgkmcnt(0)" ::: "memory");      \
    __builtin_amdgcn_sched_barrier(0);                      \
    __builtin_amdgcn_s_barrier();                           \
    __builtin_amdgcn_sched_barrier(0);                      \
} while (0)

// ---------------------------------------------------------------------------
// Kernel 1: tg_energy gather. ws[0..15] <- per-block partial sums.
// ---------------------------------------------------------------------------
__global__ __launch_bounds__(256) void tg_kernel(const float* __restrict__ scores,
                                                 const int*   __restrict__ target,
                                                 const int*   __restrict__ mask,
                                                 float*       __restrict__ ws) {
    int idx = blockIdx.x * 256 + threadIdx.x;
    float v = 0.0f;
    if (mask[idx] != 0) v = scores[(size_t)idx * TTT + target[idx]];
    #pragma unroll
    for (int off = 32; off > 0; off >>= 1) v += __shfl_down(v, off, 64);
    __shared__ float partial[4];
    int wave = threadIdx.x >> 6, lane = threadIdx.x & 63;
    if (lane == 0) partial[wave] = v;
    __syncthreads();
    if (threadIdx.x == 0)
        ws[blockIdx.x] = partial[0] + partial[1] + partial[2] + partial[3];
}

// ---------------------------------------------------------------------------
// Kernel 2: init. State layout always [first*32+second], parity0 = S_0 tag 0;
// parity1 cleared (replay-safe full overwrite).
// fwd S_0 = Q_1[i,j] = exp(p1[i] + s1[i,j]); bwd S_0 = R_127 = indicator.
// ---------------------------------------------------------------------------
__global__ __launch_bounds__(256) void init_qfb(const float* __restrict__ scores,
                                                u64* __restrict__ ptF,
                                                u64* __restrict__ ptB) {
    const int blk = blockIdx.x, tid = threadIdx.x;
    if (blk < BATCH) {
        const int b = blk;
        u64* pt = ptF + (size_t)b * 2048;
        #pragma unroll
        for (int q = 0; q < 4; ++q) {
            int e = q * 256 + tid;
            int i = e >> 5, j = e & 31;
            float p1 = scores[(size_t)(0*BATCH + b)*TTT + START*TT + START*T + i];
            float s1 = scores[(size_t)(1*BATCH + b)*TTT + START*TT + i*T + j];
            pt[e]        = pt_pack(0, __expf(p1 + s1));
            pt[1024 + e] = 0ULL;
        }
    } else {
        const int b = blk - BATCH;
        u64* pt = ptB + (size_t)b * 2048;
        #pragma unroll
        for (int q = 0; q < 4; ++q) {
            int e = q * 256 + tid;
            pt[e]        = pt_pack(0, (e == END*T + END) ? 1.0f : 0.0f);
            pt[1024 + e] = 0ULL;
        }
    }
}

// ---------------------------------------------------------------------------
// Kernel 3: fused-pair distributed fwd/bwd scan. 512 blocks x 512 threads,
// 2 blocks/CU co-resident. bid: g=bid&7, chain=bid>>3, b=chain&31, dirB=chain>=32.
// 32 units; unit = 2 steps (1 exchange). Unified algebra:
//   single step: out[a,b] = sum_p E[p,a,b] * S[p,a]
//   fused pair:  phase1 I[j,k] = sum_i E0[i,j,k] S[i,j]; phase2 = single(E1, I)
// fwd unit u: steps (2+2u, 3+2u), u=31 single t=64 -> Q_64.
// bwd unit u: steps (127-2u, 126-2u) applied high-first, u=31 single t=65 -> R_64.
// Exchange: per-word tagged u64, relaxed-only, disjoint publish chunks,
// full-state poll (2 words/thread). Tag u -> parity u&1.
// ---------------------------------------------------------------------------
__global__ __launch_bounds__(512, 4) void scan_qfb(const float* __restrict__ scores,
                                                   const int*   __restrict__ maskI,
                                                   u64*         __restrict__ ptF,
                                                   u64*         __restrict__ ptB) {
    const int bid   = blockIdx.x;
    const int g     = bid & 7;
    const int chain = bid >> 3;
    const int b     = chain & 31;
    const bool dirB = (chain >> 5) != 0;
    const int tid   = threadIdx.x;

    __shared__ __align__(16) float T1[128 * TSTR];
    __shared__ __align__(16) float T2[128 * TSTR];
    __shared__ float Sld[32 * SSTR];
    __shared__ float Ild[132];
    __shared__ int   lmask[SEQ_LEN];

    if (tid < SEQ_LEN) lmask[tid] = maskI[tid * BATCH + b];
    __syncthreads();

    u64* const pt = (dirB ? ptB : ptF) + (size_t)b * 2048;
    auto sbase = [&](int t) { return scores + ((size_t)t * BATCH + b) * TTT; };

    // mode/tiles for unit u: tP = phase1 tile t, tQ = phase2 tile t
    auto getU = [&](int u, int& tP, int& tQ, int& md) {
        if (!dirB) {
            int t0 = 2 + 2*u, t1 = (u < 31) ? 3 + 2*u : -1;
            int a0 = lmask[t0], a1 = (t1 > 0) ? lmask[t1] : 0;
            if (a0 && a1)      { md = 2; tP = t0; tQ = t1; }
            else if (a0 || a1) { md = 1; tP = -1; tQ = a0 ? t0 : t1; }
            else               { md = 0; tP = -1; tQ = -1; }
        } else {
            int th = 127 - 2*u, tl = (u < 31) ? 126 - 2*u : -1;
            int ah = lmask[th], al = (tl > 0) ? lmask[tl] : 0;
            if (ah && al)      { md = 2; tP = th; tQ = tl; }
            else if (ah || al) { md = 1; tP = ah ? th : tl; tQ = -1; }
            else               { md = 0; tP = -1; tQ = -1; }
        }
    };

    // per-thread load offsets
    size_t offP0, offP1, offQ0, offQ1;
    if (!dirB) {
        const int j = tid >> 4, q = tid & 15;
        offP0 = (size_t)q * TT + j * T + 4*g;         // TileA: E[i=q][j][Kc]
        offP1 = offP0 + (size_t)16 * TT;              //        E[i=q+16][j][Kc]
        offQ0 = (size_t)j * TT + 4*g * T + q * 8;     // TileB: E[j][Kc][l], 2 f4
        offQ1 = offQ0 + 4;
    } else {
        const int jj1 = tid >> 7, e4 = tid & 127;
        offP0 = (size_t)(4*g + jj1) * TT + e4 * 8;    // T1: E[Jc][k][l], 2 f4
        offP1 = offP0 + 4;
        const int i = tid >> 4, hA = tid & 15, jj2 = hA >> 2, h = hA & 3;
        offQ0 = (size_t)i * TT + (4*g + jj2) * T + h * 4;   // T2: E[i][Jc][k]
        offQ1 = offQ0 + 16;
    }

    float4 P0a{}, P1a{}, Q0a{}, Q1a{}, P0b{}, P1b{}, Q0b{}, Q1b{};

    auto loadRegs = [&](int u, float4& P0, float4& P1, float4& Q0, float4& Q1) {
        int tP, tQ, md; getU(u, tP, tQ, md);
        if (!dirB) {
            if (md == 2) { const float* p = sbase(tP);
                P0 = *(const float4*)(p + offP0); P1 = *(const float4*)(p + offP1); }
            if (md >= 1) { const float* p = sbase(tQ);
                Q0 = *(const float4*)(p + offQ0); Q1 = *(const float4*)(p + offQ1); }
        } else {
            if (md >= 1) { const float* p = sbase(tP);
                P0 = *(const float4*)(p + offP0); P1 = *(const float4*)(p + offP1); }
            if (md == 2) { const float* p = sbase(tQ);
                Q0 = *(const float4*)(p + offQ0); Q1 = *(const float4*)(p + offQ1); }
        }
    };

    auto scatter = [&](int md, const float4& P0, const float4& P1,
                       const float4& Q0, const float4& Q1) {
        if (!dirB) {
            if (md >= 1) {   // TileB -> T1: rows (j*4+kk), cols l
                const int j = tid >> 4, hB = tid & 15, kk = hB >> 2, l0 = 8*(hB & 3);
                *(float4*)&T1[(j*4 + kk)*TSTR + l0]     = Q0;
                *(float4*)&T1[(j*4 + kk)*TSTR + l0 + 4] = Q1;
            }
        } else {
            if (md >= 1) {   // ph1 tile -> T1: rows (jj*32+k), cols l
                const int jj = tid >> 7, e4 = tid & 127, k = e4 >> 2, l0 = 8*(e4 & 3);
                *(float4*)&T1[(jj*32 + k)*TSTR + l0]     = P0;
                *(float4*)&T1[(jj*32 + k)*TSTR + l0 + 4] = P1;
            }
            if (md == 2) {   // ph2 tile -> T2: rows (i*4+jj), cols k
                const int i = tid >> 4, hA = tid & 15, jj = hA >> 2, h = hA & 3;
                *(float4*)&T2[(i*4 + jj)*TSTR + h*4]      = Q0;
                *(float4*)&T2[(i*4 + jj)*TSTR + 16 + h*4] = Q1;
            }
        }
    };

    auto poll = [&](int u) {
        const u64* src = pt + (size_t)(u & 1) * 1024;
        const int tagw = u;
        const int x0 = 2*tid, x1 = 2*tid + 1;
        u64 w0 = 0, w1 = 0; bool d0 = false, d1 = false;
        while (true) {
            if (!d0) { w0 = ald64(src + x0); d0 = (pt_tag(w0) == tagw); }
            if (!d1) { w1 = ald64(src + x1); d1 = (pt_tag(w1) == tagw); }
            if (__all(d0 && d1)) break;
        }
        Sld[(x0 >> 5)*SSTR + (x0 & 31)] = pt_val(w0);
        Sld[(x1 >> 5)*SSTR + (x1 & 31)] = pt_val(w1);
    };

    auto phase1 = [&](int md, const float4& P0, const float4& P1) {
        if (!dirB) {
            if (md == 2) {
                const int j = tid >> 4, q = tid & 15;
                const float s0 = Sld[q*SSTR + j], s1 = Sld[(q + 16)*SSTR + j];
                float a0 = exp2f(fmaf(P0.x, LOG2E, -OFF4))*s0 + exp2f(fmaf(P1.x, LOG2E, -OFF4))*s1;
                float a1 = exp2f(fmaf(P0.y, LOG2E, -OFF4))*s0 + exp2f(fmaf(P1.y, LOG2E, -OFF4))*s1;
                float a2 = exp2f(fmaf(P0.z, LOG2E, -OFF4))*s0 + exp2f(fmaf(P1.z, LOG2E, -OFF4))*s1;
                float a3 = exp2f(fmaf(P0.w, LOG2E, -OFF4))*s0 + exp2f(fmaf(P1.w, LOG2E, -OFF4))*s1;
                #pragma unroll
                for (int m = 1; m < 16; m <<= 1) {
                    a0 += __shfl_xor(a0, m, 64); a1 += __shfl_xor(a1, m, 64);
                    a2 += __shfl_xor(a2, m, 64); a3 += __shfl_xor(a3, m, 64);
                }
                if (q == 0) { Ild[j*4+0]=a0; Ild[j*4+1]=a1; Ild[j*4+2]=a2; Ild[j*4+3]=a3; }
            } else if (md == 1) {
                if (tid < 128) { const int j = tid >> 2, kk = tid & 3;
                    Ild[j*4 + kk] = Sld[j*SSTR + 4*g + kk]; }
            }
        } else {
            if (md >= 1) {   // J[jj,k] = sum_l E[Jc,k,l] * S[k,l]
                const int jj = tid >> 7, k = (tid >> 2) & 31, r = tid & 3;
                float acc = 0.f;
                #pragma unroll
                for (int m = 0; m < 8; ++m) {
                    const int l = r + 4*m;
                    acc = fmaf(exp2f(fmaf(T1[(jj*32 + k)*TSTR + l], LOG2E, -OFF4)),
                               Sld[k*SSTR + l], acc);
                }
                acc += __shfl_xor(acc, 1, 64);
                acc += __shfl_xor(acc, 2, 64);
                if (r == 0) Ild[jj*SSTR + k] = acc;
            }
        }
    };

    auto phase2pub = [&](int u, int md) {
        u64* dst = pt + (size_t)((u + 1) & 1) * 1024;
        const int tg2 = u + 1;
        if (!dirB) {
            if (md >= 1) {   // out[k,l] = sum_j E[j,k,l] * I[j,k]
                const int kk = tid >> 7, l = (tid >> 2) & 31, r = tid & 3;
                float acc = 0.f;
                #pragma unroll
                for (int m = 0; m < 8; ++m) {
                    const int j = r + 4*m;
                    acc = fmaf(exp2f(fmaf(T1[(j*4 + kk)*TSTR + l], LOG2E, -OFF4)),
                               Ild[j*4 + kk], acc);
                }
                acc += __shfl_xor(acc, 1, 64);
                acc += __shfl_xor(acc, 2, 64);
                if (r == 0) ast64(dst + (4*g + kk)*32 + l, pt_pack(tg2, acc));
            } else {
                if (tid < 128) { const int kk = tid >> 5, l = tid & 31;
                    ast64(dst + (4*g + kk)*32 + l,
                          pt_pack(tg2, Sld[(4*g + kk)*SSTR + l])); }
            }
        } else {
            if (md == 2) {   // out[i,Jc] = sum_k E[i,Jc,k] * J[jj,k]
                const int i = tid >> 4, jj = (tid >> 2) & 3, r = tid & 3;
                float acc = 0.f;
                #pragma unroll
                for (int m = 0; m < 8; ++m) {
                    const int k = r + 4*m;
                    acc = fmaf(exp2f(fmaf(T2[(i*4 + jj)*TSTR + k], LOG2E, -OFF4)),
                               Ild[jj*SSTR + k], acc);
                }
                acc += __shfl_xor(acc, 1, 64);
                acc += __shfl_xor(acc, 2, 64);
                if (r == 0) ast64(dst + i*32 + 4*g + jj, pt_pack(tg2, acc));
            } else if (md == 1) {
                if (tid < 128) { const int jj = tid >> 5, k = tid & 31;
                    ast64(dst + (4*g + jj)*32 + k, pt_pack(tg2, Ild[jj*SSTR + k])); }
            } else {
                if (tid < 128) { const int jj = tid >> 5, k = tid & 31;
                    ast64(dst + (4*g + jj)*32 + k,
                          pt_pack(tg2, Sld[(4*g + jj)*SSTR + k])); }
            }
        }
    };

    loadRegs(0, P0a, P1a, Q0a, Q1a);
    for (int u = 0; u < 32; ++u) {
        int tP, tQ, md; getU(u, tP, tQ, md);
        if (u < 31) loadRegs(u + 1, P0b, P1b, Q0b, Q1b);
        scatter(md, P0a, P1a, Q0a, Q1a);
        poll(u);
        BLOCK_SYNC();                 // B1: Sld + tiles staged
        phase1(md, P0a, P1a);
        BLOCK_SYNC();                 // B2: Ild ready
        phase2pub(u, md);
        BLOCK_SYNC();                 // B3: LDS reads done before next overwrite
        P0a = P0b; P1a = P1b; Q0a = Q0b; Q1a = Q1b;
    }
}

// ---------------------------------------------------------------------------
// Kernel 4: finalize. Q_64 = ptF parity0 tag32, R_64 = ptB parity0 tag32,
// both layout [a*32+b]. z_b = 4*cnt_b + log(sum Q o R).
// ---------------------------------------------------------------------------
__global__ __launch_bounds__(1024) void finalize_qfb(const float* __restrict__ ws,
                                                     const u64*  __restrict__ ptF,
                                                     const u64*  __restrict__ ptB,
                                                     const int*  __restrict__ mask,
                                                     float*      __restrict__ out) {
    __shared__ float zs[32];
    const int w = threadIdx.x >> 6, lane = threadIdx.x & 63;
    for (int rep = 0; rep < 2; ++rep) {
        const int b = w + rep * 16;
        const u64* qf = ptF + (size_t)b * 2048;
        const u64* rb = ptB + (size_t)b * 2048;
        float dot = 0.f;
        #pragma unroll
        for (int e = 0; e < 16; ++e) {
            const int x = lane + 64 * e;
            dot += pt_val(qf[x]) * pt_val(rb[x]);
        }
        float cnt = 0.f;
        {
            int t = 2 + lane;
            if (t < SEQ_LEN) cnt += (mask[t*BATCH + b] != 0) ? 1.f : 0.f;
            t += 64;
            if (t < SEQ_LEN) cnt += (mask[t*BATCH + b] != 0) ? 1.f : 0.f;
        }
        #pragma unroll
        for (int off = 32; off > 0; off >>= 1) {
            dot += __shfl_xor(dot, off, 64);
            cnt += __shfl_xor(cnt, off, 64);
        }
        if (lane == 0) zs[b] = 4.0f * cnt + logf(dot);
    }
    __syncthreads();
    if (threadIdx.x == 0) {
        float tg = 0.f, z = 0.f;
        #pragma unroll
        for (int i = 0; i < 16; ++i) tg += ws[i];
        #pragma unroll
        for (int i = 0; i < 32; ++i) z += zs[i];
        out[0] = (z - tg) / (float)BATCH;
    }
}

// ---------------------------------------------------------------------------
// Fallback (small ws): round-5 single-block-per-batch scan.
// ---------------------------------------------------------------------------
__global__ __launch_bounds__(1024) void scan_fast(const float* __restrict__ scores,
                                                  const int*   __restrict__ maskI,
                                                  float*       __restrict__ ws) {
    const int b    = blockIdx.x;
    const int tid  = threadIdx.x;
    const int w    = tid >> 6;
    const int lane = tid & 63;
    const int h    = lane >> 4;
    const int jp   = (lane >> 3) & 1;
    const int k4   = lane & 7;
    const int j    = w * 2 + jp;

    __shared__ float Q[2][TT];
    __shared__ int   lmask[SEQ_LEN];
    if (tid < SEQ_LEN) lmask[tid] = maskI[tid * BATCH + b];
    {
        int x = tid >> 5, y = tid & 31;
        float p1 = scores[(size_t)(0*BATCH + b)*TTT + START*TT + START*T + x];
        float s1 = scores[(size_t)(1*BATCH + b)*TTT + START*TT + x*T + y];
        Q[1][x*T + y] = __expf(p1 + s1);
    }
    __syncthreads();
    const int loff = h*8*TT + j*T + k4*4;
    float4 SA[8], SB[8];
    auto issue = [&](float4 (&S)[8], int t) {
        const float* p = scores + ((size_t)t*BATCH + b)*TTT + loff;
        #pragma unroll
        for (int m = 0; m < 8; ++m) S[m] = *(const float4*)(p + m*TT);
    };
    auto process = [&](float4 (&S)[8], int t) {
        const float* qc = Q[(t-1) & 1];
        float*       qn = Q[t & 1];
        #pragma unroll
        for (int m = 0; m < 8; ++m) {
            S[m].x = exp2f(fmaf(S[m].x, LOG2E, -OFF4));
            S[m].y = exp2f(fmaf(S[m].y, LOG2E, -OFF4));
            S[m].z = exp2f(fmaf(S[m].z, LOG2E, -OFF4));
            S[m].w = exp2f(fmaf(S[m].w, LOG2E, -OFF4));
        }
        float4 acc = make_float4(0.f, 0.f, 0.f, 0.f);
        #pragma unroll
        for (int m = 0; m < 8; ++m) {
            float q = qc[(h*8 + m)*T + j];
            acc.x = fmaf(S[m].x, q, acc.x);
            acc.y = fmaf(S[m].y, q, acc.y);
            acc.z = fmaf(S[m].z, q, acc.z);
            acc.w = fmaf(S[m].w, q, acc.w);
        }
        acc.x += __shfl_xor(acc.x, 16, 64); acc.y += __shfl_xor(acc.y, 16, 64);
        acc.z += __shfl_xor(acc.z, 16, 64); acc.w += __shfl_xor(acc.w, 16, 64);
        acc.x += __shfl_xor(acc.x, 32, 64); acc.y += __shfl_xor(acc.y, 32, 64);
        acc.z += __shfl_xor(acc.z, 32, 64); acc.w += __shfl_xor(acc.w, 32, 64);
        if (lane < 16) {
            if (lmask[t] != 0) *(float4*)&qn[j*T + k4*4] = acc;
            else               *(float4*)&qn[j*T + k4*4] = *(const float4*)&qc[j*T + k4*4];
        }
        asm volatile("s_waitcnt lgkmcnt(0)" ::: "memory");
        __builtin_amdgcn_s_barrier();
    };
    issue(SA, 2);
    for (int t = 2; t < SEQ_LEN; t += 2) {
        issue(SB, t + 1);
        process(SA, t);
        if (t + 2 < SEQ_LEN) issue(SA, t + 2);
        process(SB, t + 1);
    }
    if (tid == 0) {
        int cnt = 0;
        for (int t = 2; t < SEQ_LEN; ++t) cnt += (lmask[t] != 0);
        ws[16 + b] = 4.0f * (float)cnt + logf(Q[1][END*T + END]);
    }
}

__global__ void finalize_simple(const float* __restrict__ ws, float* __restrict__ out) {
    if (threadIdx.x == 0) {
        float tg = 0.f, z = 0.f;
        #pragma unroll
        for (int i = 0; i < 16; ++i) tg += ws[i];
        #pragma unroll
        for (int i = 0; i < 32; ++i) z += ws[16 + i];
        out[0] = (z - tg) / (float)BATCH;
    }
}

extern "C" void kernel_launch(void* const* d_in, const int* in_sizes, int n_in,
                              void* d_out, int out_size, void* d_ws, size_t ws_size,
                              hipStream_t stream) {
    const float* scores = (const float*)d_in[0];
    const int*   target = (const int*)d_in[1];
    const int*   mask   = (const int*)d_in[2];
    float* out = (float*)d_out;
    float* ws  = (float*)d_ws;
    u64*   ptF = (u64*)((char*)d_ws + 1024);
    u64*   ptB = ptF + (size_t)BATCH * 2048;
    const size_t need = 1024 + (size_t)2 * BATCH * 2048 * sizeof(u64);   // ~1.05 MB

    tg_kernel<<<16, 256, 0, stream>>>(scores, target, mask, ws);
    if (ws_size >= need) {
        init_qfb<<<2*BATCH, 256, 0, stream>>>(scores, ptF, ptB);
        scan_qfb<<<512, 512, 0, stream>>>(scores, mask, ptF, ptB);
        finalize_qfb<<<1, 1024, 0, stream>>>(ws, ptF, ptB, mask, out);
    } else {
        scan_fast<<<BATCH, 1024, 0, stream>>>(scores, mask, ws);
        finalize_simple<<<1, 64, 0, stream>>>(ws, out);
    }
}